// Round 1
// baseline (769.153 us; speedup 1.0000x reference)
//
#include <hip/hip_runtime.h>
#include <hip/hip_bf16.h>

// Problem constants: B=32, Cin=96, H=W=56 (HW=3136), planes=576, Cout=96.
#define BATCH 32
#define CIN 96
#define HW 3136
#define PL 576
#define NHW 100352.0   // 32*3136, BN count
#define HWT 25         // ceil(3136/128)

// ---------------- ternarize: delta=0.7*mean|w|, alpha=mean(|w|>delta) -----------
__global__ __launch_bounds__(256) void tern_kernel(const float* __restrict__ w,
                                                   float* __restrict__ tw, int n) {
  __shared__ float ra[256], rb[256];
  __shared__ float sdelta, salpha;
  const int tid = threadIdx.x;
  float s = 0.f;
  for (int i = tid; i < n; i += 256) s += fabsf(w[i]);
  ra[tid] = s; __syncthreads();
  for (int off = 128; off; off >>= 1) { if (tid < off) ra[tid] += ra[tid + off]; __syncthreads(); }
  if (tid == 0) sdelta = 0.7f * (ra[0] / (float)n);
  __syncthreads();
  const float delta = sdelta;
  float sa = 0.f, sm = 0.f;
  for (int i = tid; i < n; i += 256) {
    float a = fabsf(w[i]);
    if (a > delta) { sa += a; sm += 1.f; }
  }
  ra[tid] = sa; rb[tid] = sm; __syncthreads();
  for (int off = 128; off; off >>= 1) {
    if (tid < off) { ra[tid] += ra[tid + off]; rb[tid] += rb[tid + off]; }
    __syncthreads();
  }
  if (tid == 0) salpha = ra[0] / fmaxf(rb[0], 1.f);
  __syncthreads();
  const float alpha = salpha;
  for (int i = tid; i < n; i += 256) {
    float wv = w[i];
    tw[i] = (fabsf(wv) > delta) ? copysignf(alpha, wv) : 0.f;
  }
}

// ---------------- conv1: 1x1 expand 96->576, raw out (bf16) + BN partials ------
// grid (25, 32) = (hw-tile, n). block 256. Each block: all 576 k, 128 hw.
__global__ __launch_bounds__(256) void conv1_kernel(
    const float* __restrict__ x, const float* __restrict__ tw1,
    __hip_bfloat16* __restrict__ out1,
    float* __restrict__ psum, float* __restrict__ psumsq) {
  __shared__ float xs[CIN * 128];    // 48 KB
  __shared__ float wsh[CIN * 65];    // [c][kk] padded, 24.4 KB
  const int hwt = blockIdx.x, n = blockIdx.y;
  const int t0 = hwt * 128;
  const int valid = min(128, HW - t0);
  const int tid = threadIdx.x;
  const float* xn = x + (size_t)n * CIN * HW;
  for (int i = tid; i < CIN * 32; i += 256) {
    int c = i >> 5, p4 = (i & 31) << 2;
    float4 v = make_float4(0.f, 0.f, 0.f, 0.f);
    if (p4 < valid) v = *reinterpret_cast<const float4*>(xn + (size_t)c * HW + t0 + p4);
    *reinterpret_cast<float4*>(&xs[c * 128 + p4]) = v;
  }
  __syncthreads();
  const int tx = tid & 15, ty = tid >> 4;
  const int hb = tx * 8;
  for (int kt = 0; kt < 9; ++kt) {
    const int k0 = kt * 64;
    for (int i = tid; i < 64 * CIN; i += 256) {   // i = kk*96 + c -> coalesced read
      int kk = i / CIN, c = i - kk * CIN;
      wsh[c * 65 + kk] = tw1[(size_t)(k0 + kk) * CIN + c];
    }
    __syncthreads();
    float acc[4][8];
#pragma unroll
    for (int i = 0; i < 4; ++i)
#pragma unroll
      for (int j = 0; j < 8; ++j) acc[i][j] = 0.f;
    for (int c = 0; c < CIN; ++c) {
      const float4 xa = *reinterpret_cast<const float4*>(&xs[c * 128 + hb]);
      const float4 xb = *reinterpret_cast<const float4*>(&xs[c * 128 + hb + 4]);
      const float xv[8] = {xa.x, xa.y, xa.z, xa.w, xb.x, xb.y, xb.z, xb.w};
#pragma unroll
      for (int i = 0; i < 4; ++i) {
        const float wv = wsh[c * 65 + ty * 4 + i];
#pragma unroll
        for (int j = 0; j < 8; ++j) acc[i][j] = fmaf(wv, xv[j], acc[i][j]);
      }
    }
    // BN partials (invalid hw contribute exact zeros) + bf16 store
#pragma unroll
    for (int i = 0; i < 4; ++i) {
      float s = 0.f, q = 0.f;
#pragma unroll
      for (int j = 0; j < 8; ++j) { float v = acc[i][j]; s += v; q = fmaf(v, v, q); }
      for (int m = 1; m < 16; m <<= 1) { s += __shfl_xor(s, m, 16); q += __shfl_xor(q, m, 16); }
      if (tx == 0) {
        int kg = k0 + ty * 4 + i;
        int pi = kg * 800 + n * 25 + hwt;
        psum[pi] = s; psumsq[pi] = q;
      }
    }
    if (hb < valid) {
#pragma unroll
      for (int i = 0; i < 4; ++i) {
        int kg = k0 + ty * 4 + i;
        __hip_bfloat16* o = out1 + ((size_t)n * PL + kg) * HW + t0 + hb;
        alignas(16) __hip_bfloat16 pk[8];
#pragma unroll
        for (int j = 0; j < 8; ++j) pk[j] = __float2bfloat16(acc[i][j]);
        *reinterpret_cast<uint4*>(o) = *reinterpret_cast<const uint4*>(pk);
      }
    }
    __syncthreads();
  }
}

// ---------------- BN param: sc = g*inv, sh = b - mean*g*inv ---------------------
__global__ __launch_bounds__(256) void bnp_kernel(
    const float* __restrict__ psum, const float* __restrict__ psumsq,
    const float* __restrict__ gamma, const float* __restrict__ beta,
    float* __restrict__ sc, float* __restrict__ sh, int nparts) {
  const int ch = blockIdx.x, tid = threadIdx.x;
  double s = 0.0, q = 0.0;
  for (int i = tid; i < nparts; i += 256) {
    s += (double)psum[(size_t)ch * nparts + i];
    q += (double)psumsq[(size_t)ch * nparts + i];
  }
  __shared__ double rs[256], rq[256];
  rs[tid] = s; rq[tid] = q; __syncthreads();
  for (int off = 128; off; off >>= 1) {
    if (tid < off) { rs[tid] += rs[tid + off]; rq[tid] += rq[tid + off]; }
    __syncthreads();
  }
  if (tid == 0) {
    double mean = rs[0] / NHW;
    double var = rq[0] / NHW - mean * mean;
    float inv = (float)(1.0 / sqrt(var + 1e-5));
    float g = gamma[ch];
    sc[ch] = inv * g;
    sh[ch] = beta[ch] - (float)mean * inv * g;
  }
}

// ---------------- depthwise 3x3 (in-place bf16), applies BN1+ReLU on load -------
// grid (576, 32) = (k, n). Whole 56x56 plane staged in LDS (safe for in-place).
__global__ __launch_bounds__(256) void dw_kernel(
    const __hip_bfloat16* __restrict__ in, const float* __restrict__ tw2,
    const float* __restrict__ s1, const float* __restrict__ t1,
    __hip_bfloat16* __restrict__ outp,
    float* __restrict__ psum, float* __restrict__ psumsq) {
  __shared__ float tile[58 * 60];
  __shared__ float rs[256], rq[256];
  const int k = blockIdx.x, n = blockIdx.y;
  const int tid = threadIdx.x;
  const float sc = s1[k], sh = t1[k];
  const __hip_bfloat16* p = in + ((size_t)n * PL + k) * HW;
  for (int i = tid; i < 58 * 58; i += 256) {
    int tr = i / 58, tc = i - tr * 58;
    int r = tr - 1, c = tc - 1;
    float v = 0.f;
    if ((unsigned)r < 56u && (unsigned)c < 56u)
      v = fmaxf(fmaf(__bfloat162float(p[r * 56 + c]), sc, sh), 0.f);
    tile[tr * 60 + tc] = v;
  }
  __syncthreads();
  float w[9];
#pragma unroll
  for (int i = 0; i < 9; ++i) w[i] = tw2[k * 9 + i];
  float lsum = 0.f, lsq = 0.f;
  __hip_bfloat16* o = outp + ((size_t)n * PL + k) * HW;
  for (int g = tid; g < 392; g += 256) {   // 392 groups of 8 (56 % 8 == 0: no row crossing)
    int base = g * 8;
    int r = base / 56, c0 = base - r * 56;
    alignas(16) __hip_bfloat16 pk[8];
#pragma unroll
    for (int j = 0; j < 8; ++j) {
      int c = c0 + j;
      float a = 0.f;
#pragma unroll
      for (int dy = 0; dy < 3; ++dy)
#pragma unroll
        for (int dx = 0; dx < 3; ++dx)
          a = fmaf(w[dy * 3 + dx], tile[(r + dy) * 60 + c + dx], a);
      pk[j] = __float2bfloat16(a);
      lsum += a; lsq = fmaf(a, a, lsq);
    }
    *reinterpret_cast<uint4*>(o + base) = *reinterpret_cast<const uint4*>(pk);
  }
  rs[tid] = lsum; rq[tid] = lsq; __syncthreads();
  for (int off = 128; off; off >>= 1) {
    if (tid < off) { rs[tid] += rs[tid + off]; rq[tid] += rq[tid + off]; }
    __syncthreads();
  }
  if (tid == 0) { psum[k * 32 + n] = rs[0]; psumsq[k * 32 + n] = rq[0]; }
}

// ---------------- conv3: 1x1 project 576->96, BN2+ReLU on load ------------------
// grid (25, 32). block 256. Each block: all 96 co, 128 hw, loop k-chunks of 64.
__global__ __launch_bounds__(256) void conv3_kernel(
    const __hip_bfloat16* __restrict__ y, const float* __restrict__ tw3,
    const float* __restrict__ s2, const float* __restrict__ t2,
    float* __restrict__ out3,
    float* __restrict__ psum, float* __restrict__ psumsq) {
  __shared__ float ys[64 * 128];   // 32 KB
  __shared__ float wsh[64 * 97];   // [kk][co] padded, 24.8 KB
  const int hwt = blockIdx.x, n = blockIdx.y;
  const int t0 = hwt * 128;
  const int valid = min(128, HW - t0);
  const int tid = threadIdx.x;
  const int tx = tid & 15, ty = tid >> 4;
  const int hb = tx * 8;
  float acc[6][8];
#pragma unroll
  for (int i = 0; i < 6; ++i)
#pragma unroll
    for (int j = 0; j < 8; ++j) acc[i][j] = 0.f;
  for (int c0 = 0; c0 < PL; c0 += 64) {
    for (int i = tid; i < 1024; i += 256) {     // 64 ch * 16 groups of 8
      int kk = i >> 4, p8 = (i & 15) << 3;
      int chn = c0 + kk;
      float* dst = &ys[kk * 128 + p8];
      if (p8 < valid) {
        const float scv = s2[chn], tv = t2[chn];
        uint4 raw = *reinterpret_cast<const uint4*>(y + ((size_t)n * PL + chn) * HW + t0 + p8);
        unsigned uu[4] = {raw.x, raw.y, raw.z, raw.w};
#pragma unroll
        for (int j = 0; j < 4; ++j) {
          float f0 = __uint_as_float((uu[j] & 0xffffu) << 16);
          float f1 = __uint_as_float(uu[j] & 0xffff0000u);
          dst[2 * j]     = fmaxf(fmaf(f0, scv, tv), 0.f);
          dst[2 * j + 1] = fmaxf(fmaf(f1, scv, tv), 0.f);
        }
      } else {
#pragma unroll
        for (int j = 0; j < 8; ++j) dst[j] = 0.f;
      }
    }
    for (int i = tid; i < 96 * 64; i += 256) {  // i = co*64 + kk -> coalesced read
      int co = i >> 6, kk = i & 63;
      wsh[kk * 97 + co] = tw3[(size_t)co * PL + c0 + kk];
    }
    __syncthreads();
    for (int kk = 0; kk < 64; ++kk) {
      const float4 ya = *reinterpret_cast<const float4*>(&ys[kk * 128 + hb]);
      const float4 yb = *reinterpret_cast<const float4*>(&ys[kk * 128 + hb + 4]);
      const float yv[8] = {ya.x, ya.y, ya.z, ya.w, yb.x, yb.y, yb.z, yb.w};
#pragma unroll
      for (int i = 0; i < 6; ++i) {
        const float wv = wsh[kk * 97 + ty * 6 + i];
#pragma unroll
        for (int j = 0; j < 8; ++j) acc[i][j] = fmaf(wv, yv[j], acc[i][j]);
      }
    }
    __syncthreads();
  }
#pragma unroll
  for (int i = 0; i < 6; ++i) {
    float s = 0.f, q = 0.f;
#pragma unroll
    for (int j = 0; j < 8; ++j) { float v = acc[i][j]; s += v; q = fmaf(v, v, q); }
    for (int m = 1; m < 16; m <<= 1) { s += __shfl_xor(s, m, 16); q += __shfl_xor(q, m, 16); }
    if (tx == 0) {
      int co = ty * 6 + i;
      int pi = co * 800 + n * 25 + hwt;
      psum[pi] = s; psumsq[pi] = q;
    }
  }
  if (hb < valid) {
#pragma unroll
    for (int i = 0; i < 6; ++i) {
      int co = ty * 6 + i;
      float* o = out3 + ((size_t)n * 96 + co) * HW + t0 + hb;
      float4 v0 = make_float4(acc[i][0], acc[i][1], acc[i][2], acc[i][3]);
      float4 v1 = make_float4(acc[i][4], acc[i][5], acc[i][6], acc[i][7]);
      *reinterpret_cast<float4*>(o) = v0;
      *reinterpret_cast<float4*>(o + 4) = v1;
    }
  }
}

// ---------------- final: out = BN3(out3) + x ------------------------------------
__global__ __launch_bounds__(256) void final_kernel(
    const float* __restrict__ out3, const float* __restrict__ x,
    const float* __restrict__ s3, const float* __restrict__ t3,
    float* __restrict__ out) {
  int i = blockIdx.x * 256 + threadIdx.x;   // float4 index; grid covers exactly
  int p = (i * 4) / HW;                     // n*96+co
  int co = p - (p / 96) * 96;
  float4 a = reinterpret_cast<const float4*>(out3)[i];
  float4 b = reinterpret_cast<const float4*>(x)[i];
  float scv = s3[co], tv = t3[co];
  float4 r;
  r.x = fmaf(a.x, scv, tv) + b.x;
  r.y = fmaf(a.y, scv, tv) + b.y;
  r.z = fmaf(a.z, scv, tv) + b.z;
  r.w = fmaf(a.w, scv, tv) + b.w;
  reinterpret_cast<float4*>(out)[i] = r;
}

extern "C" void kernel_launch(void* const* d_in, const int* in_sizes, int n_in,
                              void* d_out, int out_size, void* d_ws, size_t ws_size,
                              hipStream_t stream) {
  const float* x  = (const float*)d_in[0];
  const float* w1 = (const float*)d_in[1];
  const float* g1 = (const float*)d_in[2];
  const float* b1 = (const float*)d_in[3];
  const float* w2 = (const float*)d_in[4];
  const float* g2 = (const float*)d_in[5];
  const float* b2 = (const float*)d_in[6];
  const float* w3 = (const float*)d_in[7];
  const float* g3 = (const float*)d_in[8];
  const float* b3 = (const float*)d_in[9];
  float* out = (float*)d_out;

  // Workspace layout (floats). Total need: ~43.5 MB f32 region + 115.6 MB bf16
  // intermediate (depthwise runs in place) = ~152 MB.
  float* wsf = (float*)d_ws;
  float* tw1 = wsf;                       // 55296
  float* tw2 = tw1 + 55296;               // 5184
  float* tw3 = tw2 + 5184;                // 55296
  float* s1  = tw3 + 55296; float* t1 = s1 + PL;
  float* s2  = t1 + PL;     float* t2 = s2 + PL;
  float* s3  = t2 + PL;     float* t3 = s3 + 96;
  float* ps1 = t3 + 96;      float* pq1 = ps1 + PL * 800;
  float* ps2 = pq1 + PL * 800; float* pq2 = ps2 + PL * 32;
  float* ps3 = pq2 + PL * 32;  float* pq3 = ps3 + 96 * 800;
  float* out3 = pq3 + 96 * 800;           // 9,633,792 floats
  __hip_bfloat16* o1 = (__hip_bfloat16*)(out3 + 9633792);   // 57,802,752 bf16
  __hip_bfloat16* o2 = o1;                // depthwise in place

  tern_kernel<<<1, 256, 0, stream>>>(w1, tw1, PL * CIN);
  tern_kernel<<<1, 256, 0, stream>>>(w2, tw2, PL * 9);
  tern_kernel<<<1, 256, 0, stream>>>(w3, tw3, 96 * PL);

  conv1_kernel<<<dim3(HWT, BATCH), 256, 0, stream>>>(x, tw1, o1, ps1, pq1);
  bnp_kernel<<<PL, 256, 0, stream>>>(ps1, pq1, g1, b1, s1, t1, 800);

  dw_kernel<<<dim3(PL, BATCH), 256, 0, stream>>>(o1, tw2, s1, t1, o2, ps2, pq2);
  bnp_kernel<<<PL, 256, 0, stream>>>(ps2, pq2, g2, b2, s2, t2, 32);

  conv3_kernel<<<dim3(HWT, BATCH), 256, 0, stream>>>(o2, tw3, s2, t2, out3, ps3, pq3);
  bnp_kernel<<<96, 256, 0, stream>>>(ps3, pq3, g3, b3, s3, t3, 800);

  final_kernel<<<(out_size / 4 + 255) / 256, 256, 0, stream>>>(out3, x, s3, t3, out);
}

// Round 2
// 421.697 us; speedup vs baseline: 1.8239x; 1.8239x over previous
//
#include <hip/hip_runtime.h>
#include <hip/hip_bf16.h>

// B=32, Cin=96, HW=3136 (56x56), planes=576, Cout=96. hw tiles: 49 x 64 (exact).
#define BATCH 32
#define CIN 96
#define HW 3136
#define PL 576
#define COUT 96
#define NT 49
#define NHW 100352.0

typedef __attribute__((ext_vector_type(4))) float f32x4;
typedef __attribute__((ext_vector_type(8))) short s16x8;

__device__ __forceinline__ unsigned short f2b(float v) {
  __hip_bfloat16 h = __float2bfloat16(v);
  return *reinterpret_cast<unsigned short*>(&h);
}
__device__ __forceinline__ float b2f(unsigned int u) {
  return __uint_as_float((u & 0xffffu) << 16);
}

// ---------------- ternarize -> sign in {-1,0,+1} (alpha cancels in BN) ----------
__global__ __launch_bounds__(256) void tern_sign_bf16(const float* __restrict__ w,
                                                      __hip_bfloat16* __restrict__ tw, int n) {
  __shared__ float ra[256];
  __shared__ float sdelta;
  const int tid = threadIdx.x;
  float s = 0.f;
  for (int i = tid; i < n; i += 256) s += fabsf(w[i]);
  ra[tid] = s; __syncthreads();
  for (int off = 128; off; off >>= 1) { if (tid < off) ra[tid] += ra[tid + off]; __syncthreads(); }
  if (tid == 0) sdelta = 0.7f * (ra[0] / (float)n);
  __syncthreads();
  const float delta = sdelta;
  for (int i = tid; i < n; i += 256) {
    float wv = w[i];
    float sv = (fabsf(wv) > delta) ? (wv > 0.f ? 1.f : -1.f) : 0.f;
    tw[i] = __float2bfloat16(sv);
  }
}

__global__ __launch_bounds__(256) void tern_sign_f32(const float* __restrict__ w,
                                                     float* __restrict__ tw, int n) {
  __shared__ float ra[256];
  __shared__ float sdelta;
  const int tid = threadIdx.x;
  float s = 0.f;
  for (int i = tid; i < n; i += 256) s += fabsf(w[i]);
  ra[tid] = s; __syncthreads();
  for (int off = 128; off; off >>= 1) { if (tid < off) ra[tid] += ra[tid + off]; __syncthreads(); }
  if (tid == 0) sdelta = 0.7f * (ra[0] / (float)n);
  __syncthreads();
  const float delta = sdelta;
  for (int i = tid; i < n; i += 256) {
    float wv = w[i];
    tw[i] = (fabsf(wv) > delta) ? (wv > 0.f ? 1.f : -1.f) : 0.f;
  }
}

// ---------------- BN param: sc = g*inv, sh = b - mean*g*inv ---------------------
__global__ __launch_bounds__(256) void bnp_kernel(
    const float* __restrict__ psum, const float* __restrict__ psumsq,
    const float* __restrict__ gamma, const float* __restrict__ beta,
    float* __restrict__ sc, float* __restrict__ sh, int nparts) {
  const int ch = blockIdx.x, tid = threadIdx.x;
  double s = 0.0, q = 0.0;
  for (int i = tid; i < nparts; i += 256) {
    s += (double)psum[(size_t)ch * nparts + i];
    q += (double)psumsq[(size_t)ch * nparts + i];
  }
  __shared__ double rs[256], rq[256];
  rs[tid] = s; rq[tid] = q; __syncthreads();
  for (int off = 128; off; off >>= 1) {
    if (tid < off) { rs[tid] += rs[tid + off]; rq[tid] += rq[tid + off]; }
    __syncthreads();
  }
  if (tid == 0) {
    double mean = rs[0] / NHW;
    double var = rq[0] / NHW - mean * mean;
    float inv = (float)(1.0 / sqrt(var + 1e-5));
    float g = gamma[ch];
    sc[ch] = inv * g;
    sh[ch] = beta[ch] - (float)mean * inv * g;
  }
}

// ---------------- conv1: 1x1 expand 96->576 via bf16 MFMA -----------------------
// grid (49, 32, 3): hw-tile 64, batch, M-tile 192. block 256 (4 waves x 48 rows).
__global__ __launch_bounds__(256) void conv1_mfma(
    const float* __restrict__ x, const __hip_bfloat16* __restrict__ tw1,
    __hip_bfloat16* __restrict__ out1,
    float* __restrict__ psum, float* __restrict__ psumsq) {
  __shared__ float smem[192 * 65];   // 49.9 KB; start doubles as bf16 B-tile [64][104]
  __hip_bfloat16* Bt = reinterpret_cast<__hip_bfloat16*>(smem);
  const int hwt = blockIdx.x, n = blockIdx.y, mt = blockIdx.z;
  const int t0 = hwt * 64;
  const int tid = threadIdx.x;
  const int lane = tid & 63, w = tid >> 6;

  // stage B: x[c][t0+lane] -> Bt[lane][c] (bf16, row stride 104)
  {
    const float* xp = x + (size_t)n * CIN * HW + t0 + lane;
    const int cb = w * 24;
#pragma unroll
    for (int i6 = 0; i6 < 6; ++i6) {
      const int c0 = cb + i6 * 4;
      float v0 = xp[(size_t)(c0 + 0) * HW];
      float v1 = xp[(size_t)(c0 + 1) * HW];
      float v2 = xp[(size_t)(c0 + 2) * HW];
      float v3 = xp[(size_t)(c0 + 3) * HW];
      unsigned lo = (unsigned)f2b(v0) | ((unsigned)f2b(v1) << 16);
      unsigned hi = (unsigned)f2b(v2) | ((unsigned)f2b(v3) << 16);
      *reinterpret_cast<uint2*>(&Bt[lane * 104 + c0]) = make_uint2(lo, hi);
    }
  }
  __syncthreads();

  const int l15 = lane & 15, lh = lane >> 4;
  f32x4 acc[3][4];
#pragma unroll
  for (int f = 0; f < 3; ++f)
#pragma unroll
    for (int g = 0; g < 4; ++g) acc[f][g] = (f32x4){0.f, 0.f, 0.f, 0.f};
  const int rowb = mt * 192 + w * 48;
#pragma unroll
  for (int k0 = 0; k0 < 3; ++k0) {
    s16x8 a[3], b[4];
#pragma unroll
    for (int f = 0; f < 3; ++f)
      a[f] = *reinterpret_cast<const s16x8*>(tw1 + (size_t)(rowb + f * 16 + l15) * CIN + k0 * 32 + lh * 8);
#pragma unroll
    for (int g = 0; g < 4; ++g)
      b[g] = *reinterpret_cast<const s16x8*>(&Bt[(g * 16 + l15) * 104 + k0 * 32 + lh * 8]);
#pragma unroll
    for (int f = 0; f < 3; ++f)
#pragma unroll
      for (int g = 0; g < 4; ++g)
        acc[f][g] = __builtin_amdgcn_mfma_f32_16x16x32_bf16(a[f], b[g], acc[f][g], 0, 0, 0);
  }
  __syncthreads();

  // bounce acc -> LDS f32 [192][65]
#pragma unroll
  for (int f = 0; f < 3; ++f)
#pragma unroll
    for (int g = 0; g < 4; ++g)
#pragma unroll
      for (int r = 0; r < 4; ++r)
        smem[(w * 48 + f * 16 + lh * 4 + r) * 65 + g * 16 + l15] = acc[f][g][r];
  __syncthreads();

  // epilogue: coalesced bf16 stores + BN partials
  const int slot = tid & 7, rgrp = tid >> 3;
#pragma unroll
  for (int s = 0; s < 6; ++s) {
    const int rl = s * 32 + rgrp;
    float v[8], sm = 0.f, sq = 0.f;
#pragma unroll
    for (int j = 0; j < 8; ++j) {
      float t = smem[rl * 65 + slot * 8 + j];
      v[j] = t; sm += t; sq = fmaf(t, t, sq);
    }
    unsigned pk[4];
#pragma unroll
    for (int j = 0; j < 4; ++j) pk[j] = (unsigned)f2b(v[2 * j]) | ((unsigned)f2b(v[2 * j + 1]) << 16);
    const int cout = mt * 192 + rl;
    *reinterpret_cast<uint4*>(out1 + ((size_t)n * PL + cout) * HW + t0 + slot * 8) =
        make_uint4(pk[0], pk[1], pk[2], pk[3]);
#pragma unroll
    for (int m = 1; m < 8; m <<= 1) { sm += __shfl_xor(sm, m, 8); sq += __shfl_xor(sq, m, 8); }
    if (slot == 0) { int pi = cout * 1568 + n * NT + hwt; psum[pi] = sm; psumsq[pi] = sq; }
  }
}

// ---------------- depthwise 3x3 in-place, BN1+ReLU on load ----------------------
__global__ __launch_bounds__(256) void dw_kernel(
    const __hip_bfloat16* __restrict__ in, const float* __restrict__ tw2,
    const float* __restrict__ s1, const float* __restrict__ t1,
    __hip_bfloat16* __restrict__ outp,
    float* __restrict__ psum, float* __restrict__ psumsq) {
  __shared__ float tile[58 * 60];
  __shared__ float rs[256], rq[256];
  const int k = blockIdx.x, n = blockIdx.y, tid = threadIdx.x;
  const float sc = s1[k], sh = t1[k];
  const __hip_bfloat16* p = in + ((size_t)n * PL + k) * HW;
  if (tid < 58) { tile[tid] = 0.f; tile[57 * 60 + tid] = 0.f; }
  if (tid < 56) { tile[(tid + 1) * 60] = 0.f; tile[(tid + 1) * 60 + 57] = 0.f; }
  for (int idx = tid; idx < 392; idx += 256) {
    const int r = idx / 7, g = idx - r * 7;
    uint4 raw = *reinterpret_cast<const uint4*>(p + r * 56 + g * 8);
    unsigned u[4] = {raw.x, raw.y, raw.z, raw.w};
    float* dst = &tile[(r + 1) * 60 + 1 + g * 8];
#pragma unroll
    for (int j = 0; j < 4; ++j) {
      dst[2 * j]     = fmaxf(fmaf(b2f(u[j]), sc, sh), 0.f);
      dst[2 * j + 1] = fmaxf(fmaf(b2f(u[j] >> 16), sc, sh), 0.f);
    }
  }
  __syncthreads();
  float wv[9];
#pragma unroll
  for (int i = 0; i < 9; ++i) wv[i] = tw2[k * 9 + i];
  float lsum = 0.f, lsq = 0.f;
  __hip_bfloat16* o = outp + ((size_t)n * PL + k) * HW;
  for (int g = tid; g < 392; g += 256) {
    const int r = g / 7, c0 = (g - r * 7) * 8;
    float av[8];
#pragma unroll
    for (int j = 0; j < 8; ++j) {
      const int c = c0 + j;
      float a = 0.f;
#pragma unroll
      for (int dy = 0; dy < 3; ++dy)
#pragma unroll
        for (int dx = 0; dx < 3; ++dx)
          a = fmaf(wv[dy * 3 + dx], tile[(r + dy) * 60 + c + dx], a);
      av[j] = a; lsum += a; lsq = fmaf(a, a, lsq);
    }
    unsigned pk[4];
#pragma unroll
    for (int j = 0; j < 4; ++j) pk[j] = (unsigned)f2b(av[2 * j]) | ((unsigned)f2b(av[2 * j + 1]) << 16);
    *reinterpret_cast<uint4*>(o + r * 56 + c0) = make_uint4(pk[0], pk[1], pk[2], pk[3]);
  }
  rs[tid] = lsum; rq[tid] = lsq; __syncthreads();
  for (int off = 128; off; off >>= 1) {
    if (tid < off) { rs[tid] += rs[tid + off]; rq[tid] += rq[tid + off]; }
    __syncthreads();
  }
  if (tid == 0) { psum[k * 32 + n] = rs[0]; psumsq[k * 32 + n] = rq[0]; }
}

// ---------------- conv3: 1x1 project 576->96 via bf16 MFMA, BN2+ReLU on load ----
// grid (49, 32). block 256 = 4 waves in 2x2 (48 rows x 32 cols each).
__global__ __launch_bounds__(256) void conv3_mfma(
    const __hip_bfloat16* __restrict__ y, const __hip_bfloat16* __restrict__ tw3,
    const float* __restrict__ s2, const float* __restrict__ t2,
    __hip_bfloat16* __restrict__ out3,
    float* __restrict__ psum, float* __restrict__ psumsq) {
  __shared__ float smem[96 * 65];    // 24.96 KB; start doubles as bf16 B-tile [64][104]
  __shared__ float s2s[PL], t2s[PL];
  __hip_bfloat16* Bt = reinterpret_cast<__hip_bfloat16*>(smem);
  const int hwt = blockIdx.x, n = blockIdx.y;
  const int t0 = hwt * 64, tid = threadIdx.x;
  const int lane = tid & 63, w = tid >> 6;
  const int l15 = lane & 15, lh = lane >> 4;
  const int wm = w >> 1, wn = w & 1;
  for (int i = tid; i < PL; i += 256) { s2s[i] = s2[i]; t2s[i] = t2[i]; }

  f32x4 acc[3][2];
#pragma unroll
  for (int f = 0; f < 3; ++f)
#pragma unroll
    for (int g = 0; g < 2; ++g) acc[f][g] = (f32x4){0.f, 0.f, 0.f, 0.f};

  const __hip_bfloat16* yp = y + (size_t)n * PL * HW + t0 + lane;
  const int cb = w * 24;
  for (int ck = 0; ck < 6; ++ck) {
    __syncthreads();   // covers s2s preload (ck=0) and prior-chunk B reads
#pragma unroll
    for (int i6 = 0; i6 < 6; ++i6) {
      const int cl = cb + i6 * 4;        // chunk-local c
      const int c0 = ck * 96 + cl;
      float vv[4];
#pragma unroll
      for (int j = 0; j < 4; ++j) {
        float t = __bfloat162float(yp[(size_t)(c0 + j) * HW]);
        vv[j] = fmaxf(fmaf(t, s2s[c0 + j], t2s[c0 + j]), 0.f);
      }
      unsigned lo = (unsigned)f2b(vv[0]) | ((unsigned)f2b(vv[1]) << 16);
      unsigned hi = (unsigned)f2b(vv[2]) | ((unsigned)f2b(vv[3]) << 16);
      *reinterpret_cast<uint2*>(&Bt[lane * 104 + cl]) = make_uint2(lo, hi);
    }
    __syncthreads();
#pragma unroll
    for (int k0 = 0; k0 < 3; ++k0) {
      s16x8 a[3], b[2];
#pragma unroll
      for (int f = 0; f < 3; ++f)
        a[f] = *reinterpret_cast<const s16x8*>(tw3 + (size_t)(wm * 48 + f * 16 + l15) * PL + ck * 96 + k0 * 32 + lh * 8);
#pragma unroll
      for (int g = 0; g < 2; ++g)
        b[g] = *reinterpret_cast<const s16x8*>(&Bt[(wn * 32 + g * 16 + l15) * 104 + k0 * 32 + lh * 8]);
#pragma unroll
      for (int f = 0; f < 3; ++f)
#pragma unroll
        for (int g = 0; g < 2; ++g)
          acc[f][g] = __builtin_amdgcn_mfma_f32_16x16x32_bf16(a[f], b[g], acc[f][g], 0, 0, 0);
    }
  }
  __syncthreads();
#pragma unroll
  for (int f = 0; f < 3; ++f)
#pragma unroll
    for (int g = 0; g < 2; ++g)
#pragma unroll
      for (int r = 0; r < 4; ++r)
        smem[(wm * 48 + f * 16 + lh * 4 + r) * 65 + wn * 32 + g * 16 + l15] = acc[f][g][r];
  __syncthreads();

  const int slot = tid & 7, rgrp = tid >> 3;
#pragma unroll
  for (int s = 0; s < 3; ++s) {
    const int rl = s * 32 + rgrp;
    float v[8], sm = 0.f, sq = 0.f;
#pragma unroll
    for (int j = 0; j < 8; ++j) {
      float t = smem[rl * 65 + slot * 8 + j];
      v[j] = t; sm += t; sq = fmaf(t, t, sq);
    }
    unsigned pk[4];
#pragma unroll
    for (int j = 0; j < 4; ++j) pk[j] = (unsigned)f2b(v[2 * j]) | ((unsigned)f2b(v[2 * j + 1]) << 16);
    *reinterpret_cast<uint4*>(out3 + ((size_t)n * COUT + rl) * HW + t0 + slot * 8) =
        make_uint4(pk[0], pk[1], pk[2], pk[3]);
#pragma unroll
    for (int m = 1; m < 8; m <<= 1) { sm += __shfl_xor(sm, m, 8); sq += __shfl_xor(sq, m, 8); }
    if (slot == 0) { int pi = rl * 1568 + n * NT + hwt; psum[pi] = sm; psumsq[pi] = sq; }
  }
}

// ---------------- final: out = BN3(out3_bf16) + x -------------------------------
__global__ __launch_bounds__(256) void final_kernel(
    const __hip_bfloat16* __restrict__ out3, const float* __restrict__ x,
    const float* __restrict__ s3, const float* __restrict__ t3,
    float* __restrict__ out) {
  const int i = blockIdx.x * 256 + threadIdx.x;   // float4 index, grid exact
  const int p = (i * 4) / HW;
  const int co = p - (p / COUT) * COUT;
  uint2 raw = reinterpret_cast<const uint2*>(out3)[i];
  float4 b = reinterpret_cast<const float4*>(x)[i];
  const float scv = s3[co], tv = t3[co];
  float4 r;
  r.x = fmaf(b2f(raw.x), scv, tv) + b.x;
  r.y = fmaf(b2f(raw.x >> 16), scv, tv) + b.y;
  r.z = fmaf(b2f(raw.y), scv, tv) + b.z;
  r.w = fmaf(b2f(raw.y >> 16), scv, tv) + b.w;
  reinterpret_cast<float4*>(out)[i] = r;
}

extern "C" void kernel_launch(void* const* d_in, const int* in_sizes, int n_in,
                              void* d_out, int out_size, void* d_ws, size_t ws_size,
                              hipStream_t stream) {
  const float* x  = (const float*)d_in[0];
  const float* w1 = (const float*)d_in[1];
  const float* g1 = (const float*)d_in[2];
  const float* b1 = (const float*)d_in[3];
  const float* w2 = (const float*)d_in[4];
  const float* g2 = (const float*)d_in[5];
  const float* b2 = (const float*)d_in[6];
  const float* w3 = (const float*)d_in[7];
  const float* g3 = (const float*)d_in[8];
  const float* b3 = (const float*)d_in[9];
  float* out = (float*)d_out;

  char* ws = (char*)d_ws;
  __hip_bfloat16* tw1b = (__hip_bfloat16*)(ws + 0);            // 110592 B
  __hip_bfloat16* tw3b = (__hip_bfloat16*)(ws + 110592);       // 110592 B
  float* tw2f = (float*)(ws + 221184);                          // 20736 B
  float* s1 = (float*)(ws + 241920);
  float* t1 = s1 + PL; float* s2 = t1 + PL; float* t2 = s2 + PL;
  float* s3 = (float*)(ws + 251136); float* t3 = s3 + COUT;
  float* ps1 = (float*)(ws + 251904);                           // 576*1568
  float* pq1 = ps1 + PL * 1568;
  float* ps2 = pq1 + PL * 1568;                                 // 576*32
  float* pq2 = ps2 + PL * 32;
  float* ps3 = pq2 + PL * 32;                                   // 96*1568
  float* pq3 = ps3 + COUT * 1568;
  __hip_bfloat16* out3b = (__hip_bfloat16*)(pq3 + COUT * 1568); // 19.3 MB
  __hip_bfloat16* o1 = out3b + (size_t)BATCH * COUT * HW;       // 115.6 MB

  tern_sign_bf16<<<1, 256, 0, stream>>>(w1, tw1b, PL * CIN);
  tern_sign_f32 <<<1, 256, 0, stream>>>(w2, tw2f, PL * 9);
  tern_sign_bf16<<<1, 256, 0, stream>>>(w3, tw3b, COUT * PL);

  conv1_mfma<<<dim3(NT, BATCH, 3), 256, 0, stream>>>(x, tw1b, o1, ps1, pq1);
  bnp_kernel<<<PL, 256, 0, stream>>>(ps1, pq1, g1, b1, s1, t1, 1568);

  dw_kernel<<<dim3(PL, BATCH), 256, 0, stream>>>(o1, tw2f, s1, t1, o1, ps2, pq2);
  bnp_kernel<<<PL, 256, 0, stream>>>(ps2, pq2, g2, b2, s2, t2, 32);

  conv3_mfma<<<dim3(NT, BATCH), 256, 0, stream>>>(o1, tw3b, s2, t2, out3b, ps3, pq3);
  bnp_kernel<<<COUT, 256, 0, stream>>>(ps3, pq3, g3, b3, s3, t3, 1568);

  final_kernel<<<out_size / 1024, 256, 0, stream>>>(out3b, x, s3, t3, out);
}